// Round 1
// 1034.832 us; speedup vs baseline: 3.9187x; 3.9187x over previous
//
#include <hip/hip_runtime.h>

// ============================================================================
// WindowAttention fused kernel v2: bf16 MFMA with double-bf16 (hi/lo) split.
//   D = Ah*Bh + Ah*Bl + Al*Bh  (fp32 accum)  -> ~2^-16 per-product rel error.
// One block per window, 256 threads (4 waves), wave w owns token rows 16w..+15.
// S computed transposed (mfma(K,Q)) so P^T accum regs ARE the PV B-fragment and
// O^T accum regs ARE the proj A-fragment: no LDS staging for P or O.
// Prep kernel pre-splits weights into MFMA fragment layout in d_ws; bias is
// pre-gathered into C-init fragments; softmax scale folded into q weights.
// ============================================================================

constexpr int NT = 64, DIMC = 192, NH = 6;
constexpr float SC = 0.17677669529663687f;  // 32^-0.5

typedef short          s8v __attribute__((ext_vector_type(8)));  // 8 bf16 (4 VGPR)
typedef float          f4v __attribute__((ext_vector_type(4)));
typedef unsigned short u4v __attribute__((ext_vector_type(4)));

// ---- workspace layout (bytes) ----
constexpr size_t WS_QKVW  = 0;                              // 36nt*6kk*2sp frags * 1024B
constexpr size_t WS_PROJW = WS_QKVW + (size_t)36*6*2*1024;  // = 442368
constexpr size_t WS_BIAS  = WS_PROJW + (size_t)12*6*2*1024; // +147456 = 589824
constexpr size_t WS_QKVB  = WS_BIAS + (size_t)6*4*4*64*16;  // +98304  = 688128
constexpr size_t WS_NEED  = WS_QKVB + (size_t)576*4;        // 690432

__device__ __forceinline__ unsigned short bhi(float x) {       // truncate to bf16
  return (unsigned short)(__builtin_bit_cast(unsigned int, x) >> 16);
}
__device__ __forceinline__ float bft(unsigned short h) {       // bf16 -> f32
  return __builtin_bit_cast(float, ((unsigned int)h) << 16);
}
__device__ __forceinline__ unsigned short brne(float x) {      // RNE to bf16
  unsigned int u = __builtin_bit_cast(unsigned int, x);
  u += 0x7FFFu + ((u >> 16) & 1u);
  return (unsigned short)(u >> 16);
}

#define MFMA16(a, b, c) __builtin_amdgcn_mfma_f32_16x16x32_bf16((a), (b), (c), 0, 0, 0)

// build an 8-elem fragment from LDS: 4 bf16 at idx, 4 bf16 at idx+16
__device__ __forceinline__ s8v ld_frag(const unsigned short* base, int idx) {
  u4v a = *(const u4v*)(base + idx);
  u4v b = *(const u4v*)(base + idx + 16);
  s8v r;
  #pragma unroll
  for (int i = 0; i < 4; ++i) { r[i] = (short)a[i]; r[4 + i] = (short)b[i]; }
  return r;
}

// ============================================================================
// prep kernel: split/scale weights into fragment layout; gather bias fragments.
// frag(lane, reg): m/n = 16*tile + (lane&15); k = 4*(lane>>4)+{0..3} (+16 regs 4-7)
// ============================================================================
__global__ __launch_bounds__(256) void prep_kernel(
    const float* __restrict__ qkv_w, const float* __restrict__ qkv_b,
    const float* __restrict__ proj_w, const float* __restrict__ rpb,
    const int* __restrict__ ridx, char* __restrict__ ws)
{
  const int t = blockIdx.x * 256 + threadIdx.x;
  if (t < 13824) {                      // qkv_w: 36 ntiles x 6 ksteps x 64 lanes
    const int lane = t & 63, rest = t >> 6;
    const int kk = rest % 6, nt = rest / 6;
    const int g = lane >> 4, c = lane & 15;
    const int n = 16 * nt + c;          // qkv output row (0..575)
    const float sc = (nt < 12) ? SC : 1.f;   // fold softmax scale into q rows
    const float* p = qkv_w + n * 192 + kk * 32 + 4 * g;
    f4v a = *(const f4v*)p;       a *= sc;
    f4v b = *(const f4v*)(p + 16); b *= sc;
    s8v hi, lo;
    #pragma unroll
    for (int i = 0; i < 4; ++i) {
      unsigned short h0 = bhi(a[i]); hi[i]     = (short)h0; lo[i]     = (short)brne(a[i] - bft(h0));
      unsigned short h1 = bhi(b[i]); hi[4 + i] = (short)h1; lo[4 + i] = (short)brne(b[i] - bft(h1));
    }
    s8v* base = (s8v*)(ws + WS_QKVW);
    base[((nt * 6 + kk) * 2 + 0) * 64 + lane] = hi;
    base[((nt * 6 + kk) * 2 + 1) * 64 + lane] = lo;
  } else if (t < 18432) {               // proj_w: 12 ntiles x 6 heads x 64 lanes
    const int t2 = t - 13824;
    const int lane = t2 & 63, rest = t2 >> 6;
    const int h = rest % 6, nt = rest / 6;
    const int g = lane >> 4, c = lane & 15;
    const int n = 16 * nt + c;          // output channel o
    const float* p = proj_w + n * 192 + 32 * h + 4 * g;
    f4v a = *(const f4v*)p;
    f4v b = *(const f4v*)(p + 16);
    s8v hi, lo;
    #pragma unroll
    for (int i = 0; i < 4; ++i) {
      unsigned short h0 = bhi(a[i]); hi[i]     = (short)h0; lo[i]     = (short)brne(a[i] - bft(h0));
      unsigned short h1 = bhi(b[i]); hi[4 + i] = (short)h1; lo[4 + i] = (short)brne(b[i] - bft(h1));
    }
    s8v* base = (s8v*)(ws + WS_PROJW);
    base[((nt * 6 + h) * 2 + 0) * 64 + lane] = hi;
    base[((nt * 6 + h) * 2 + 1) * 64 + lane] = lo;
  } else if (t < 24576) {               // bias C-init frags: S^T[k_][q] layout
    const int t2 = t - 18432;
    const int lane = t2 & 63, rest = t2 >> 6;     // rest 0..95
    const int nt = rest & 3, mt = (rest >> 2) & 3, h = rest >> 4;
    const int g = lane >> 4, c = lane & 15;
    const int q = 16 * nt + c;          // query token (S^T column)
    const int kb = 16 * mt + 4 * g;     // key token base (S^T rows)
    const int* ip = ridx + q * 64 + kb;
    f4v o;
    #pragma unroll
    for (int r = 0; r < 4; ++r) o[r] = rpb[ip[r] * 6 + h];
    ((f4v*)(ws + WS_BIAS))[((h * 4 + mt) * 4 + nt) * 64 + lane] = o;
  } else if (t < 25152) {               // qkv bias (q part pre-scaled)
    const int i = t - 24576;
    ((float*)(ws + WS_QKVB))[i] = qkv_b[i] * (i < 192 ? SC : 1.f);
  }
}

// ============================================================================
// main MFMA kernel
// ============================================================================
__global__ __launch_bounds__(256, 2)
void win_attn_mfma(const float* __restrict__ x, const float* __restrict__ proj_b,
                   const char* __restrict__ ws, float* __restrict__ out)
{
  // LDS staging (bf16 hi/lo, padded strides for conflict-free b64 reads)
  __shared__ alignas(16) unsigned short Qh[64 * 36], Ql[64 * 36];   // [tok][dim0..31]
  __shared__ alignas(16) unsigned short Kh[64 * 36], Kl[64 * 36];   // [tok][dim0..31]
  __shared__ alignas(16) unsigned short Vh[32 * 68], Vl[32 * 68];   // V^T: [dim][tok]

  const int tid = threadIdx.x;
  const int wv = tid >> 6, lane = tid & 63, g = lane >> 4, c = lane & 15;
  const size_t win = blockIdx.x;
  const float* xw   = x   + win * (size_t)(NT * DIMC);
  float*       outw = out + win * (size_t)(NT * DIMC);

  const s8v*   qkvw  = (const s8v*)(ws + WS_QKVW);
  const s8v*   projw = (const s8v*)(ws + WS_PROJW);
  const f4v*   biasf = (const f4v*)(ws + WS_BIAS);
  const float* qkvb  = (const float*)(ws + WS_QKVB);

  // persistent proj accumulators: out rows 16wv+4g+r, cols 16nt+c
  f4v pacc[12];
  #pragma unroll
  for (int i = 0; i < 12; ++i)
    #pragma unroll
    for (int r = 0; r < 4; ++r) pacc[i][r] = 0.f;

  const float* xbase = xw + (size_t)(16 * wv + c) * DIMC + 4 * g;

  #pragma unroll 1
  for (int h = 0; h < NH; ++h) {
    // ================= stage 1: QKV for head h =================
    // tiles sgj: 0,1=q 2,3=k 4,5=v ; D[tok][col], wave's M-tile = wv
    f4v acc[6];
    #pragma unroll
    for (int j = 0; j < 6; ++j)
      #pragma unroll
      for (int r = 0; r < 4; ++r) acc[j][r] = 0.f;

    #pragma unroll
    for (int kk = 0; kk < 6; ++kk) {
      f4v xa = *(const f4v*)(xbase + 32 * kk);
      f4v xb = *(const f4v*)(xbase + 32 * kk + 16);
      s8v ah, al;               // A-frag: x[tok=16wv+c][k=32kk+4g+i (+16)]
      #pragma unroll
      for (int i = 0; i < 4; ++i) {
        unsigned short h0 = bhi(xa[i]); ah[i]     = (short)h0; al[i]     = (short)brne(xa[i] - bft(h0));
        unsigned short h1 = bhi(xb[i]); ah[4 + i] = (short)h1; al[4 + i] = (short)brne(xb[i] - bft(h1));
      }
      #pragma unroll
      for (int sgj = 0; sgj < 6; ++sgj) {
        const int seg = sgj >> 1, j = sgj & 1;
        const int n576 = seg * 12 + 2 * h + j;       // qkv row-tile index
        const s8v bh = qkvw[((n576 * 6 + kk) * 2 + 0) * 64 + lane];
        const s8v bl = qkvw[((n576 * 6 + kk) * 2 + 1) * 64 + lane];
        acc[sgj] = MFMA16(ah, bh, acc[sgj]);
        acc[sgj] = MFMA16(ah, bl, acc[sgj]);
        acc[sgj] = MFMA16(al, bh, acc[sgj]);
      }
    }
    // epilogue: add qkv bias, split, stage to LDS
    #pragma unroll
    for (int sgj = 0; sgj < 6; ++sgj) {
      const int seg = sgj >> 1, j = sgj & 1;
      const float bv = qkvb[seg * 192 + 32 * h + 16 * j + c];
      if (seg < 2) {                       // Q, K: [tok][dim] stride 36
        unsigned short* dh = (seg == 0) ? Qh : Kh;
        unsigned short* dl = (seg == 0) ? Ql : Kl;
        #pragma unroll
        for (int r = 0; r < 4; ++r) {
          const float v = acc[sgj][r] + bv;
          const unsigned short hh = bhi(v);
          dh[(16 * wv + 4 * g + r) * 36 + 16 * j + c] = hh;
          dl[(16 * wv + 4 * g + r) * 36 + 16 * j + c] = brne(v - bft(hh));
        }
      } else {                             // V^T: [dim][tok] stride 68, packed b64
        u4v hh, ll;
        #pragma unroll
        for (int r = 0; r < 4; ++r) {
          const float v = acc[sgj][r] + bv;
          const unsigned short x0 = bhi(v);
          hh[r] = x0; ll[r] = brne(v - bft(x0));
        }
        *(u4v*)&Vh[(16 * j + c) * 68 + 16 * wv + 4 * g] = hh;
        *(u4v*)&Vl[(16 * j + c) * 68 + 16 * wv + 4 * g] = ll;
      }
    }
    __syncthreads();   // B1: Q/K/V^T visible

    // ================= stage 2: S^T = K @ Q^T + bias, softmax =================
    // wave wv owns S^T n-tile wv (query cols 16wv..+15), all 4 k-token m-tiles
    f4v sacc[4];
    #pragma unroll
    for (int mt = 0; mt < 4; ++mt)
      sacc[mt] = biasf[((h * 4 + mt) * 4 + wv) * 64 + lane];

    s8v qbh, qbl;       // B-frag: Q[qtok=16wv+c][dim 4g+i (+16)]
    {
      const int idx = (16 * wv + c) * 36 + 4 * g;
      qbh = ld_frag(Qh, idx);
      qbl = ld_frag(Ql, idx);
    }
    #pragma unroll
    for (int mt = 0; mt < 4; ++mt) {
      const int idx = (16 * mt + c) * 36 + 4 * g;   // A-frag: K[ktok=16mt+c][dim]
      const s8v kh = ld_frag(Kh, idx);
      const s8v kl = ld_frag(Kl, idx);
      sacc[mt] = MFMA16(kh, qbh, sacc[mt]);
      sacc[mt] = MFMA16(kh, qbl, sacc[mt]);
      sacc[mt] = MFMA16(kl, qbh, sacc[mt]);
    }
    // softmax over k_ (16 regs per lane + lane-groups via xor 16, 32)
    float mx = sacc[0][0];
    #pragma unroll
    for (int mt = 0; mt < 4; ++mt)
      #pragma unroll
      for (int r = 0; r < 4; ++r) mx = fmaxf(mx, sacc[mt][r]);
    mx = fmaxf(mx, __shfl_xor(mx, 16));
    mx = fmaxf(mx, __shfl_xor(mx, 32));
    float sum = 0.f;
    float p[4][4];
    #pragma unroll
    for (int mt = 0; mt < 4; ++mt)
      #pragma unroll
      for (int r = 0; r < 4; ++r) { p[mt][r] = __expf(sacc[mt][r] - mx); sum += p[mt][r]; }
    sum += __shfl_xor(sum, 16);
    sum += __shfl_xor(sum, 32);
    const float inv = 1.f / sum;
    unsigned short ph[4][4], pl[4][4];
    #pragma unroll
    for (int mt = 0; mt < 4; ++mt)
      #pragma unroll
      for (int r = 0; r < 4; ++r) {
        const float v = p[mt][r] * inv;
        const unsigned short h0 = bhi(v);
        ph[mt][r] = h0; pl[mt][r] = brne(v - bft(h0));
      }

    // ================= stage 3: O^T = V^T @ P^T =================
    // P^T accum regs are exactly the B-fragment: k = 16mt+4g+r
    f4v oa0, oa1;
    #pragma unroll
    for (int r = 0; r < 4; ++r) { oa0[r] = 0.f; oa1[r] = 0.f; }
    #pragma unroll
    for (int kk = 0; kk < 2; ++kk) {
      s8v pbh, pbl;
      #pragma unroll
      for (int i = 0; i < 4; ++i) {
        pbh[i] = (short)ph[2 * kk][i];     pbl[i] = (short)pl[2 * kk][i];
        pbh[4 + i] = (short)ph[2 * kk + 1][i]; pbl[4 + i] = (short)pl[2 * kk + 1][i];
      }
      #pragma unroll
      for (int mo = 0; mo < 2; ++mo) {
        const int idx = (16 * mo + c) * 68 + 32 * kk + 4 * g;  // A-frag: V^T[dim][tok]
        const s8v vh = ld_frag(Vh, idx);
        const s8v vl = ld_frag(Vl, idx);
        f4v& o = (mo == 0) ? oa0 : oa1;
        o = MFMA16(vh, pbh, o);
        o = MFMA16(vh, pbl, o);
        o = MFMA16(vl, pbh, o);
      }
    }
    __syncthreads();   // B2: all LDS reads of this head done; next head may restage

    // ================= stage 4: proj accumulation =================
    // O^T accum regs are exactly the proj A-fragment: m=16wv+c, k(dim)=4g+i (+16)
    s8v oh, ol;
    #pragma unroll
    for (int i = 0; i < 4; ++i) {
      const unsigned short h0 = bhi(oa0[i]);
      oh[i] = (short)h0; ol[i] = (short)brne(oa0[i] - bft(h0));
      const unsigned short h1 = bhi(oa1[i]);
      oh[4 + i] = (short)h1; ol[4 + i] = (short)brne(oa1[i] - bft(h1));
    }
    #pragma unroll
    for (int nt = 0; nt < 12; ++nt) {
      const s8v wh = projw[((nt * 6 + h) * 2 + 0) * 64 + lane];
      const s8v wl = projw[((nt * 6 + h) * 2 + 1) * 64 + lane];
      pacc[nt] = MFMA16(oh, wh, pacc[nt]);
      pacc[nt] = MFMA16(oh, wl, pacc[nt]);
      pacc[nt] = MFMA16(ol, wh, pacc[nt]);
    }
  }

  // ================= epilogue =================
  #pragma unroll
  for (int nt = 0; nt < 12; ++nt) {
    const float pb = proj_b[16 * nt + c];
    #pragma unroll
    for (int r = 0; r < 4; ++r)
      outw[(size_t)(16 * wv + 4 * g + r) * DIMC + 16 * nt + c] = pacc[nt][r] + pb;
  }
}

// ============================================================================
// fallback: previous verified fp32 kernel (used only if workspace too small)
// ============================================================================
__global__ __launch_bounds__(256, 2)
void win_attn_kernel(const float* __restrict__ x, const float* __restrict__ qkv_w,
                     const float* __restrict__ qkv_b, const float* __restrict__ proj_w,
                     const float* __restrict__ proj_b, const float* __restrict__ rpb,
                     const int* __restrict__ ridx, float* __restrict__ out)
{
  __shared__ float reg1[32 * 192];
  __shared__ float reg2[48 * 64];
  __shared__ float qs[64 * 36];
  __shared__ float ks[64 * 36];
  __shared__ float vs[64 * 36];

  const int tid = threadIdx.x;
  const int w = blockIdx.x;
  const float* xw = x + (size_t)w * (NT * DIMC);
  float* outw = out + (size_t)w * (NT * DIMC);

  const int cg = tid >> 4;
  const int tgA = tid & 15;
  const int tB = tid >> 2;
  const int jB = tid & 3;
  const int ogD = tid >> 4;
  const int tgD = tid & 15;

  int idxv[16];
  #pragma unroll
  for (int mm = 0; mm < 16; ++mm) idxv[mm] = ridx[tB * 64 + jB + 4 * mm] * NH;

  float oacc[4][12];
  #pragma unroll
  for (int tt = 0; tt < 4; ++tt)
    #pragma unroll
    for (int oo = 0; oo < 12; ++oo) oacc[tt][oo] = 0.f;

  for (int h = 0; h < NH; ++h) {
    float acc[6][4];
    #pragma unroll
    for (int cc = 0; cc < 6; ++cc)
      #pragma unroll
      for (int tt = 0; tt < 4; ++tt) acc[cc][tt] = 0.f;

    for (int i0 = 0; i0 < DIMC; i0 += 48) {
      __syncthreads();
      #pragma unroll
      for (int k = 0; k < 12; ++k) {
        int flat = k * 256 + tid;
        int t = flat & 63, ii = flat >> 6;
        reg2[ii * 64 + t] = xw[t * DIMC + i0 + ii];
      }
      #pragma unroll
      for (int k = 0; k < 18; ++k) {
        int flat = k * 256 + tid;
        int rr = flat % 96, ii = flat / 96;
        int seg = rr >> 5, lc = rr & 31;
        int grow = seg * 192 + h * 32 + lc;
        reg1[ii * 96 + rr] = qkv_w[grow * DIMC + i0 + ii];
      }
      __syncthreads();
      #pragma unroll 2
      for (int i = 0; i < 48; ++i) {
        float4 x4 = *(const float4*)(&reg2[i * 64 + 4 * tgA]);
        const float* wr = &reg1[i * 96 + 6 * cg];
        float2 w0 = *(const float2*)(wr + 0);
        float2 w1 = *(const float2*)(wr + 2);
        float2 w2 = *(const float2*)(wr + 4);
        float xa[4] = {x4.x, x4.y, x4.z, x4.w};
        float wa[6] = {w0.x, w0.y, w1.x, w1.y, w2.x, w2.y};
        #pragma unroll
        for (int cc = 0; cc < 6; ++cc)
          #pragma unroll
          for (int tt = 0; tt < 4; ++tt)
            acc[cc][tt] = fmaf(wa[cc], xa[tt], acc[cc][tt]);
      }
    }
    #pragma unroll
    for (int cc = 0; cc < 6; ++cc) {
      int cch = 6 * cg + cc;
      int seg = cch >> 5, lc = cch & 31;
      float bv = qkv_b[seg * 192 + h * 32 + lc];
      if (seg == 0) {
        #pragma unroll
        for (int tt = 0; tt < 4; ++tt)
          qs[(4 * tgA + tt) * 36 + lc] = (acc[cc][tt] + bv) * SC;
      } else if (seg == 1) {
        #pragma unroll
        for (int tt = 0; tt < 4; ++tt)
          ks[(4 * tgA + tt) * 36 + lc] = acc[cc][tt] + bv;
      } else {
        #pragma unroll
        for (int tt = 0; tt < 4; ++tt)
          vs[(4 * tgA + tt) * 36 + lc] = acc[cc][tt] + bv;
      }
    }
    __syncthreads();

    #pragma unroll
    for (int k = 0; k < 24; ++k) {
      int flat = k * 256 + tid;
      int o = flat % 192, ccc = flat / 192;
      reg1[ccc * 192 + o] = proj_w[o * DIMC + h * 32 + ccc];
    }

    float qr[32];
    {
      const float* qrow = &qs[tB * 36];
      #pragma unroll
      for (int d4 = 0; d4 < 8; ++d4) {
        float4 q4 = *(const float4*)(qrow + 4 * d4);
        qr[4*d4+0] = q4.x; qr[4*d4+1] = q4.y; qr[4*d4+2] = q4.z; qr[4*d4+3] = q4.w;
      }
    }
    float sv[16];
    #pragma unroll
    for (int mm = 0; mm < 16; ++mm) {
      const float* krow = &ks[(jB + 4 * mm) * 36];
      float a = rpb[idxv[mm] + h];
      #pragma unroll
      for (int d4 = 0; d4 < 8; ++d4) {
        float4 k4 = *(const float4*)(krow + 4 * d4);
        a = fmaf(qr[4*d4+0], k4.x, a);
        a = fmaf(qr[4*d4+1], k4.y, a);
        a = fmaf(qr[4*d4+2], k4.z, a);
        a = fmaf(qr[4*d4+3], k4.w, a);
      }
      sv[mm] = a;
    }
    float mx = sv[0];
    #pragma unroll
    for (int mm = 1; mm < 16; ++mm) mx = fmaxf(mx, sv[mm]);
    mx = fmaxf(mx, __shfl_xor(mx, 1));
    mx = fmaxf(mx, __shfl_xor(mx, 2));
    float sum = 0.f;
    #pragma unroll
    for (int mm = 0; mm < 16; ++mm) { sv[mm] = __expf(sv[mm] - mx); sum += sv[mm]; }
    sum += __shfl_xor(sum, 1);
    sum += __shfl_xor(sum, 2);
    const float inv = 1.f / sum;

    float part[32];
    #pragma unroll
    for (int dd = 0; dd < 32; ++dd) part[dd] = 0.f;
    #pragma unroll
    for (int mm = 0; mm < 16; ++mm) {
      float pv = sv[mm] * inv;
      const float* vrow = &vs[(jB + 4 * mm) * 36];
      #pragma unroll
      for (int d4 = 0; d4 < 8; ++d4) {
        float4 v4 = *(const float4*)(vrow + 4 * d4);
        part[4*d4+0] = fmaf(pv, v4.x, part[4*d4+0]);
        part[4*d4+1] = fmaf(pv, v4.y, part[4*d4+1]);
        part[4*d4+2] = fmaf(pv, v4.z, part[4*d4+2]);
        part[4*d4+3] = fmaf(pv, v4.w, part[4*d4+3]);
      }
    }
    float p16[16];
    {
      const bool hi2 = (jB & 1);
      #pragma unroll
      for (int k2 = 0; k2 < 16; ++k2) {
        float lo_v = part[k2], hi_v = part[16 + k2];
        float sendv = hi2 ? lo_v : hi_v;
        float keepv = hi2 ? hi_v : lo_v;
        float got = __shfl_xor(sendv, 1);
        p16[k2] = keepv + got;
      }
    }
    float p8[8];
    {
      const bool hi2 = (jB & 2);
      #pragma unroll
      for (int k2 = 0; k2 < 8; ++k2) {
        float lo_v = p16[k2], hi_v = p16[8 + k2];
        float sendv = hi2 ? lo_v : hi_v;
        float keepv = hi2 ? hi_v : lo_v;
        float got = __shfl_xor(sendv, 2);
        p8[k2] = keepv + got;
      }
    }
    const int dd0 = (jB & 1) * 16 + (jB & 2) * 4;
    #pragma unroll
    for (int k2 = 0; k2 < 8; ++k2)
      reg2[(dd0 + k2) * 64 + tB] = p8[k2];

    __syncthreads();

    {
      const int o0 = 12 * ogD, t0 = 4 * tgD;
      #pragma unroll 2
      for (int cc2 = 0; cc2 < 32; ++cc2) {
        float4 a4 = *(const float4*)(&reg2[cc2 * 64 + t0]);
        const float* pr = &reg1[cc2 * 192 + o0];
        float4 b0 = *(const float4*)(pr + 0);
        float4 b1 = *(const float4*)(pr + 4);
        float4 b2 = *(const float4*)(pr + 8);
        float av[4]  = {a4.x, a4.y, a4.z, a4.w};
        float bw[12] = {b0.x, b0.y, b0.z, b0.w, b1.x, b1.y, b1.z, b1.w,
                        b2.x, b2.y, b2.z, b2.w};
        #pragma unroll
        for (int tt = 0; tt < 4; ++tt)
          #pragma unroll
          for (int oo = 0; oo < 12; ++oo)
            oacc[tt][oo] = fmaf(av[tt], bw[oo], oacc[tt][oo]);
      }
    }
  }

  {
    const int o0 = 12 * ogD, t0 = 4 * tgD;
    #pragma unroll
    for (int oo = 0; oo < 12; ++oo) {
      float pb = proj_b[o0 + oo];
      #pragma unroll
      for (int tt = 0; tt < 4; ++tt)
        outw[(size_t)(t0 + tt) * DIMC + o0 + oo] = oacc[tt][oo] + pb;
    }
  }
}

extern "C" void kernel_launch(void* const* d_in, const int* in_sizes, int n_in,
                              void* d_out, int out_size, void* d_ws, size_t ws_size,
                              hipStream_t stream) {
  const float* x      = (const float*)d_in[0];
  const float* qkv_w  = (const float*)d_in[1];
  const float* qkv_b  = (const float*)d_in[2];
  const float* proj_w = (const float*)d_in[3];
  const float* proj_b = (const float*)d_in[4];
  const float* rpb    = (const float*)d_in[5];
  const int*   ridx   = (const int*)d_in[6];
  float* out = (float*)d_out;
  const int B = in_sizes[0] / (NT * DIMC);   // 4096 windows

  if (d_ws != nullptr && ws_size >= WS_NEED) {
    hipLaunchKernelGGL(prep_kernel, dim3(99), dim3(256), 0, stream,
                       qkv_w, qkv_b, proj_w, rpb, ridx, (char*)d_ws);
    hipLaunchKernelGGL(win_attn_mfma, dim3(B), dim3(256), 0, stream,
                       x, proj_b, (const char*)d_ws, out);
  } else {
    hipLaunchKernelGGL(win_attn_kernel, dim3(B), dim3(256), 0, stream,
                       x, qkv_w, qkv_b, proj_w, proj_b, rpb, ridx, out);
  }
}

// Round 2
// 937.449 us; speedup vs baseline: 4.3258x; 1.1039x over previous
//
#include <hip/hip_runtime.h>

// ============================================================================
// WindowAttention fused kernel v3: bf16 MFMA double-bf16 emulation +
// head-level software pipeline with double-buffered LDS.
//   - One barrier per head (6 total, was 12): Q/K/V LDS double-buffered.
//   - QKV for head h+1 (108 MFMAs + 72 L2 loads, fully independent) is placed
//     inside head h's attention body -> fills softmax/LDS-read stalls.
//   - proj[h] deferred to iteration h+1: independent MFMAs right after the
//     barrier where S-stage waits on LDS.
//   - softmax normalization deferred to O-split: the cross-lane sum reduce
//     overlaps PV MFMAs; P fed unnormalized (bounded by 1), inv folded into O.
// ============================================================================

constexpr int NT = 64, DIMC = 192, NH = 6;
constexpr float SC = 0.17677669529663687f;  // 32^-0.5

typedef short          s8v __attribute__((ext_vector_type(8)));  // 8 bf16 (4 VGPR)
typedef float          f4v __attribute__((ext_vector_type(4)));
typedef unsigned short u4v __attribute__((ext_vector_type(4)));

// ---- workspace layout (bytes) ----
constexpr size_t WS_QKVW  = 0;                              // 36nt*6kk*2sp frags * 1024B
constexpr size_t WS_PROJW = WS_QKVW + (size_t)36*6*2*1024;  // = 442368
constexpr size_t WS_BIAS  = WS_PROJW + (size_t)12*6*2*1024; // +147456 = 589824
constexpr size_t WS_QKVB  = WS_BIAS + (size_t)6*4*4*64*16;  // +98304  = 688128
constexpr size_t WS_NEED  = WS_QKVB + (size_t)576*4;        // 690432

__device__ __forceinline__ unsigned short bhi(float x) {       // truncate to bf16
  return (unsigned short)(__builtin_bit_cast(unsigned int, x) >> 16);
}
__device__ __forceinline__ float bft(unsigned short h) {       // bf16 -> f32
  return __builtin_bit_cast(float, ((unsigned int)h) << 16);
}
__device__ __forceinline__ unsigned short brne(float x) {      // RNE to bf16
  unsigned int u = __builtin_bit_cast(unsigned int, x);
  u += 0x7FFFu + ((u >> 16) & 1u);
  return (unsigned short)(u >> 16);
}

#define MFMA16(a, b, c) __builtin_amdgcn_mfma_f32_16x16x32_bf16((a), (b), (c), 0, 0, 0)

// build an 8-elem fragment from LDS: 4 bf16 at idx, 4 bf16 at idx+16
__device__ __forceinline__ s8v ld_frag(const unsigned short* base, int idx) {
  u4v a = *(const u4v*)(base + idx);
  u4v b = *(const u4v*)(base + idx + 16);
  s8v r;
  #pragma unroll
  for (int i = 0; i < 4; ++i) { r[i] = (short)a[i]; r[4 + i] = (short)b[i]; }
  return r;
}

// ============================================================================
// prep kernel: split/scale weights into fragment layout; gather bias fragments.
// frag(lane, reg): m/n = 16*tile + (lane&15); k = 4*(lane>>4)+{0..3} (+16 regs 4-7)
// ============================================================================
__global__ __launch_bounds__(256) void prep_kernel(
    const float* __restrict__ qkv_w, const float* __restrict__ qkv_b,
    const float* __restrict__ proj_w, const float* __restrict__ rpb,
    const int* __restrict__ ridx, char* __restrict__ ws)
{
  const int t = blockIdx.x * 256 + threadIdx.x;
  if (t < 13824) {                      // qkv_w: 36 ntiles x 6 ksteps x 64 lanes
    const int lane = t & 63, rest = t >> 6;
    const int kk = rest % 6, nt = rest / 6;
    const int g = lane >> 4, c = lane & 15;
    const int n = 16 * nt + c;          // qkv output row (0..575)
    const float sc = (nt < 12) ? SC : 1.f;   // fold softmax scale into q rows
    const float* p = qkv_w + n * 192 + kk * 32 + 4 * g;
    f4v a = *(const f4v*)p;       a *= sc;
    f4v b = *(const f4v*)(p + 16); b *= sc;
    s8v hi, lo;
    #pragma unroll
    for (int i = 0; i < 4; ++i) {
      unsigned short h0 = bhi(a[i]); hi[i]     = (short)h0; lo[i]     = (short)brne(a[i] - bft(h0));
      unsigned short h1 = bhi(b[i]); hi[4 + i] = (short)h1; lo[4 + i] = (short)brne(b[i] - bft(h1));
    }
    s8v* base = (s8v*)(ws + WS_QKVW);
    base[((nt * 6 + kk) * 2 + 0) * 64 + lane] = hi;
    base[((nt * 6 + kk) * 2 + 1) * 64 + lane] = lo;
  } else if (t < 18432) {               // proj_w: 12 ntiles x 6 heads x 64 lanes
    const int t2 = t - 13824;
    const int lane = t2 & 63, rest = t2 >> 6;
    const int h = rest % 6, nt = rest / 6;
    const int g = lane >> 4, c = lane & 15;
    const int n = 16 * nt + c;          // output channel o
    const float* p = proj_w + n * 192 + 32 * h + 4 * g;
    f4v a = *(const f4v*)p;
    f4v b = *(const f4v*)(p + 16);
    s8v hi, lo;
    #pragma unroll
    for (int i = 0; i < 4; ++i) {
      unsigned short h0 = bhi(a[i]); hi[i]     = (short)h0; lo[i]     = (short)brne(a[i] - bft(h0));
      unsigned short h1 = bhi(b[i]); hi[4 + i] = (short)h1; lo[4 + i] = (short)brne(b[i] - bft(h1));
    }
    s8v* base = (s8v*)(ws + WS_PROJW);
    base[((nt * 6 + h) * 2 + 0) * 64 + lane] = hi;
    base[((nt * 6 + h) * 2 + 1) * 64 + lane] = lo;
  } else if (t < 24576) {               // bias C-init frags: S^T[k_][q] layout
    const int t2 = t - 18432;
    const int lane = t2 & 63, rest = t2 >> 6;     // rest 0..95
    const int nt = rest & 3, mt = (rest >> 2) & 3, h = rest >> 4;
    const int g = lane >> 4, c = lane & 15;
    const int q = 16 * nt + c;          // query token (S^T column)
    const int kb = 16 * mt + 4 * g;     // key token base (S^T rows)
    const int* ip = ridx + q * 64 + kb;
    f4v o;
    #pragma unroll
    for (int r = 0; r < 4; ++r) o[r] = rpb[ip[r] * 6 + h];
    ((f4v*)(ws + WS_BIAS))[((h * 4 + mt) * 4 + nt) * 64 + lane] = o;
  } else if (t < 25152) {               // qkv bias (q part pre-scaled)
    const int i = t - 24576;
    ((float*)(ws + WS_QKVB))[i] = qkv_b[i] * (i < 192 ? SC : 1.f);
  }
}

// ============================================================================
// device helpers for the main kernel
// ============================================================================

// QKV GEMM for head h: wave's 16 tokens x 96 cols, 108 MFMAs. No LDS access.
__device__ __forceinline__ void qkv_head(int lane, const float* __restrict__ xbase,
                                         const s8v* __restrict__ qkvw,
                                         int h, f4v acc[6]) {
  #pragma unroll
  for (int j = 0; j < 6; ++j)
    #pragma unroll
    for (int r = 0; r < 4; ++r) acc[j][r] = 0.f;
  #pragma unroll
  for (int kk = 0; kk < 6; ++kk) {
    f4v xa = *(const f4v*)(xbase + 32 * kk);
    f4v xb = *(const f4v*)(xbase + 32 * kk + 16);
    s8v ah, al;               // A-frag: x[tok=16wv+c][k=32kk+4g+i (+16)]
    #pragma unroll
    for (int i = 0; i < 4; ++i) {
      unsigned short h0 = bhi(xa[i]); ah[i]     = (short)h0; al[i]     = (short)brne(xa[i] - bft(h0));
      unsigned short h1 = bhi(xb[i]); ah[4 + i] = (short)h1; al[4 + i] = (short)brne(xb[i] - bft(h1));
    }
    #pragma unroll
    for (int sgj = 0; sgj < 6; ++sgj) {
      const int seg = sgj >> 1, j = sgj & 1;
      const int n576 = seg * 12 + 2 * h + j;       // qkv row-tile index
      const s8v bh = qkvw[((n576 * 6 + kk) * 2 + 0) * 64 + lane];
      const s8v bl = qkvw[((n576 * 6 + kk) * 2 + 1) * 64 + lane];
      acc[sgj] = MFMA16(ah, bh, acc[sgj]);
      acc[sgj] = MFMA16(ah, bl, acc[sgj]);
      acc[sgj] = MFMA16(al, bh, acc[sgj]);
    }
  }
}

// add bias, split hi/lo, stage Q/K/V^T for head h into the given buffers
__device__ __forceinline__ void qkv_stage(int wv, int g, int c,
    const f4v acc[6], const float* __restrict__ qkvb, int h,
    unsigned short* Qh_, unsigned short* Ql_,
    unsigned short* Kh_, unsigned short* Kl_,
    unsigned short* Vh_, unsigned short* Vl_) {
  #pragma unroll
  for (int sgj = 0; sgj < 6; ++sgj) {
    const int seg = sgj >> 1, j = sgj & 1;
    const float bv = qkvb[seg * 192 + 32 * h + 16 * j + c];
    if (seg < 2) {                       // Q, K: [tok][dim] stride 36
      unsigned short* dh = (seg == 0) ? Qh_ : Kh_;
      unsigned short* dl = (seg == 0) ? Ql_ : Kl_;
      #pragma unroll
      for (int r = 0; r < 4; ++r) {
        const float v = acc[sgj][r] + bv;
        const unsigned short hh = bhi(v);
        dh[(16 * wv + 4 * g + r) * 36 + 16 * j + c] = hh;
        dl[(16 * wv + 4 * g + r) * 36 + 16 * j + c] = brne(v - bft(hh));
      }
    } else {                             // V^T: [dim][tok] stride 68, packed b64
      u4v hh, ll;
      #pragma unroll
      for (int r = 0; r < 4; ++r) {
        const float v = acc[sgj][r] + bv;
        const unsigned short x0 = bhi(v);
        hh[r] = x0; ll[r] = brne(v - bft(x0));
      }
      *(u4v*)&Vh_[(16 * j + c) * 68 + 16 * wv + 4 * g] = hh;
      *(u4v*)&Vl_[(16 * j + c) * 68 + 16 * wv + 4 * g] = ll;
    }
  }
}

// proj accumulation for head h from O fragments (register-only, 36 MFMAs)
__device__ __forceinline__ void proj_acc(int lane, const s8v oh, const s8v ol,
                                         const s8v* __restrict__ projw, int h,
                                         f4v pacc[12]) {
  #pragma unroll
  for (int nt = 0; nt < 12; ++nt) {
    const s8v wh = projw[((nt * 6 + h) * 2 + 0) * 64 + lane];
    const s8v wl = projw[((nt * 6 + h) * 2 + 1) * 64 + lane];
    pacc[nt] = MFMA16(oh, wh, pacc[nt]);
    pacc[nt] = MFMA16(oh, wl, pacc[nt]);
    pacc[nt] = MFMA16(ol, wh, pacc[nt]);
  }
}

// attention for head h (reads current buffers) with QKV[h+1] interleaved
// (computes into acc2 and stages into next buffers when DO_NEXT).
template<bool DO_NEXT>
__device__ __forceinline__ void head_iter(
    int h, int lane, int wv, int g, int c,
    const float* __restrict__ xbase,
    const s8v* __restrict__ qkvw, const f4v* __restrict__ biasf,
    const float* __restrict__ qkvb,
    const unsigned short* Qhc, const unsigned short* Qlc,
    const unsigned short* Khc, const unsigned short* Klc,
    const unsigned short* Vhc, const unsigned short* Vlc,
    unsigned short* Qhn, unsigned short* Qln,
    unsigned short* Khn, unsigned short* Kln,
    unsigned short* Vhn, unsigned short* Vln,
    s8v& oh, s8v& ol)
{
  // ---- S^T = K @ Q^T + bias ----
  f4v sacc[4];
  #pragma unroll
  for (int mt = 0; mt < 4; ++mt)
    sacc[mt] = biasf[((h * 4 + mt) * 4 + wv) * 64 + lane];
  s8v qbh, qbl;       // B-frag: Q[qtok=16wv+c][dim 4g+i (+16)]
  {
    const int idx = (16 * wv + c) * 36 + 4 * g;
    qbh = ld_frag(Qhc, idx);
    qbl = ld_frag(Qlc, idx);
  }
  #pragma unroll
  for (int mt = 0; mt < 4; ++mt) {
    const int idx = (16 * mt + c) * 36 + 4 * g;   // A-frag: K[ktok=16mt+c][dim]
    const s8v kh = ld_frag(Khc, idx);
    const s8v kl = ld_frag(Klc, idx);
    sacc[mt] = MFMA16(kh, qbh, sacc[mt]);
    sacc[mt] = MFMA16(kh, qbl, sacc[mt]);
    sacc[mt] = MFMA16(kl, qbh, sacc[mt]);
  }

  // ---- QKV for head h+1: fully independent of this head's attention.
  //      Placed here so the scheduler fills softmax/PV stalls with it. ----
  f4v acc2[6];
  if (DO_NEXT) qkv_head(lane, xbase, qkvw, h + 1, acc2);

  // ---- softmax (unnormalized; inv deferred to O-split) ----
  float mx = sacc[0][0];
  #pragma unroll
  for (int mt = 0; mt < 4; ++mt)
    #pragma unroll
    for (int r = 0; r < 4; ++r) mx = fmaxf(mx, sacc[mt][r]);
  mx = fmaxf(mx, __shfl_xor(mx, 16));
  mx = fmaxf(mx, __shfl_xor(mx, 32));
  float pv[4][4];
  float sum = 0.f;
  #pragma unroll
  for (int mt = 0; mt < 4; ++mt)
    #pragma unroll
    for (int r = 0; r < 4; ++r) { pv[mt][r] = __expf(sacc[mt][r] - mx); sum += pv[mt][r]; }

  // ---- PV: O^T = V^T @ P^T (P^T accum regs ARE the B-fragment) ----
  f4v oa0, oa1;
  #pragma unroll
  for (int r = 0; r < 4; ++r) { oa0[r] = 0.f; oa1[r] = 0.f; }
  #pragma unroll
  for (int kk = 0; kk < 2; ++kk) {
    s8v pbh, pbl;
    #pragma unroll
    for (int i = 0; i < 4; ++i) {
      const float v0 = pv[2 * kk][i];
      const float v1 = pv[2 * kk + 1][i];
      const unsigned short h0 = bhi(v0), h1 = bhi(v1);
      pbh[i]     = (short)h0; pbl[i]     = (short)brne(v0 - bft(h0));
      pbh[4 + i] = (short)h1; pbl[4 + i] = (short)brne(v1 - bft(h1));
    }
    #pragma unroll
    for (int mo = 0; mo < 2; ++mo) {
      const int idx = (16 * mo + c) * 68 + 32 * kk + 4 * g;  // A-frag: V^T[dim][tok]
      const s8v vh = ld_frag(Vhc, idx);
      const s8v vl = ld_frag(Vlc, idx);
      f4v& o = (mo == 0) ? oa0 : oa1;
      o = MFMA16(vh, pbh, o);
      o = MFMA16(vh, pbl, o);
      o = MFMA16(vl, pbh, o);
    }
  }
  // cross-lane sum reduce (overlaps PV MFMAs above)
  sum += __shfl_xor(sum, 16);
  sum += __shfl_xor(sum, 32);
  const float inv = 1.f / sum;

  // ---- O-split (normalize here): O^T accum regs ARE the proj A-fragment ----
  #pragma unroll
  for (int i = 0; i < 4; ++i) {
    const float v0 = oa0[i] * inv;
    const unsigned short h0 = bhi(v0);
    oh[i] = (short)h0; ol[i] = (short)brne(v0 - bft(h0));
    const float v1 = oa1[i] * inv;
    const unsigned short h1 = bhi(v1);
    oh[4 + i] = (short)h1; ol[4 + i] = (short)brne(v1 - bft(h1));
  }

  // ---- stage head h+1 into the other buffer ----
  if (DO_NEXT) qkv_stage(wv, g, c, acc2, qkvb, h + 1, Qhn, Qln, Khn, Kln, Vhn, Vln);
}

// ============================================================================
// main MFMA kernel
// ============================================================================
__global__ __launch_bounds__(256, 2)
void win_attn_mfma(const float* __restrict__ x, const float* __restrict__ proj_b,
                   const char* __restrict__ ws, float* __restrict__ out)
{
  // double-buffered LDS staging (bf16 hi/lo, padded strides, conflict-free)
  __shared__ alignas(16) unsigned short QhS[2][64 * 36], QlS[2][64 * 36];
  __shared__ alignas(16) unsigned short KhS[2][64 * 36], KlS[2][64 * 36];
  __shared__ alignas(16) unsigned short VhS[2][32 * 68], VlS[2][32 * 68];
  // total: 2*27136 = 54272 B -> 2 blocks/CU

  const int tid = threadIdx.x;
  const int wv = tid >> 6, lane = tid & 63, g = lane >> 4, c = lane & 15;
  const size_t win = blockIdx.x;
  const float* xw   = x   + win * (size_t)(NT * DIMC);
  float*       outw = out + win * (size_t)(NT * DIMC);

  const s8v*   qkvw  = (const s8v*)(ws + WS_QKVW);
  const s8v*   projw = (const s8v*)(ws + WS_PROJW);
  const f4v*   biasf = (const f4v*)(ws + WS_BIAS);
  const float* qkvb  = (const float*)(ws + WS_QKVB);

  // persistent proj accumulators: out rows 16wv+4g+r, cols 16nt+c
  f4v pacc[12];
  #pragma unroll
  for (int i = 0; i < 12; ++i)
    #pragma unroll
    for (int r = 0; r < 4; ++r) pacc[i][r] = 0.f;

  const float* xbase = xw + (size_t)(16 * wv + c) * DIMC + 4 * g;

  // ---- prologue: QKV for head 0 into buffer 0 ----
  {
    f4v acc0[6];
    qkv_head(lane, xbase, qkvw, 0, acc0);
    qkv_stage(wv, g, c, acc0, qkvb, 0,
              QhS[0], QlS[0], KhS[0], KlS[0], VhS[0], VlS[0]);
  }
  __syncthreads();

  s8v oh{}, ol{};

  // ---- h = 0 (peeled: no pending proj) ----
  head_iter<true>(0, lane, wv, g, c, xbase, qkvw, biasf, qkvb,
                  QhS[0], QlS[0], KhS[0], KlS[0], VhS[0], VlS[0],
                  QhS[1], QlS[1], KhS[1], KlS[1], VhS[1], VlS[1],
                  oh, ol);
  __syncthreads();

  // ---- h = 1..4: proj[h-1] first (independent MFMAs after the barrier) ----
  #pragma unroll 1
  for (int h = 1; h < NH - 1; ++h) {
    const int p = h & 1;
    proj_acc(lane, oh, ol, projw, h - 1, pacc);
    head_iter<true>(h, lane, wv, g, c, xbase, qkvw, biasf, qkvb,
                    QhS[p], QlS[p], KhS[p], KlS[p], VhS[p], VlS[p],
                    QhS[p ^ 1], QlS[p ^ 1], KhS[p ^ 1], KlS[p ^ 1],
                    VhS[p ^ 1], VlS[p ^ 1],
                    oh, ol);
    __syncthreads();
  }

  // ---- h = 5 (tail: no next head) ----
  proj_acc(lane, oh, ol, projw, 4, pacc);
  head_iter<false>(5, lane, wv, g, c, xbase, qkvw, biasf, qkvb,
                   QhS[1], QlS[1], KhS[1], KlS[1], VhS[1], VlS[1],
                   QhS[0], QlS[0], KhS[0], KlS[0], VhS[0], VlS[0],
                   oh, ol);
  proj_acc(lane, oh, ol, projw, 5, pacc);

  // ---- epilogue ----
  #pragma unroll
  for (int nt = 0; nt < 12; ++nt) {
    const float pb = proj_b[16 * nt + c];
    #pragma unroll
    for (int r = 0; r < 4; ++r)
      outw[(size_t)(16 * wv + 4 * g + r) * DIMC + 16 * nt + c] = pacc[nt][r] + pb;
  }
}

// ============================================================================
// fallback: verified fp32 kernel (used only if workspace too small)
// ============================================================================
__global__ __launch_bounds__(256, 2)
void win_attn_kernel(const float* __restrict__ x, const float* __restrict__ qkv_w,
                     const float* __restrict__ qkv_b, const float* __restrict__ proj_w,
                     const float* __restrict__ proj_b, const float* __restrict__ rpb,
                     const int* __restrict__ ridx, float* __restrict__ out)
{
  __shared__ float reg1[32 * 192];
  __shared__ float reg2[48 * 64];
  __shared__ float qs[64 * 36];
  __shared__ float ks[64 * 36];
  __shared__ float vs[64 * 36];

  const int tid = threadIdx.x;
  const int w = blockIdx.x;
  const float* xw = x + (size_t)w * (NT * DIMC);
  float* outw = out + (size_t)w * (NT * DIMC);

  const int cg = tid >> 4;
  const int tgA = tid & 15;
  const int tB = tid >> 2;
  const int jB = tid & 3;
  const int ogD = tid >> 4;
  const int tgD = tid & 15;

  int idxv[16];
  #pragma unroll
  for (int mm = 0; mm < 16; ++mm) idxv[mm] = ridx[tB * 64 + jB + 4 * mm] * NH;

  float oacc[4][12];
  #pragma unroll
  for (int tt = 0; tt < 4; ++tt)
    #pragma unroll
    for (int oo = 0; oo < 12; ++oo) oacc[tt][oo] = 0.f;

  for (int h = 0; h < NH; ++h) {
    float acc[6][4];
    #pragma unroll
    for (int cc = 0; cc < 6; ++cc)
      #pragma unroll
      for (int tt = 0; tt < 4; ++tt) acc[cc][tt] = 0.f;

    for (int i0 = 0; i0 < DIMC; i0 += 48) {
      __syncthreads();
      #pragma unroll
      for (int k = 0; k < 12; ++k) {
        int flat = k * 256 + tid;
        int t = flat & 63, ii = flat >> 6;
        reg2[ii * 64 + t] = xw[t * DIMC + i0 + ii];
      }
      #pragma unroll
      for (int k = 0; k < 18; ++k) {
        int flat = k * 256 + tid;
        int rr = flat % 96, ii = flat / 96;
        int seg = rr >> 5, lc = rr & 31;
        int grow = seg * 192 + h * 32 + lc;
        reg1[ii * 96 + rr] = qkv_w[grow * DIMC + i0 + ii];
      }
      __syncthreads();
      #pragma unroll 2
      for (int i = 0; i < 48; ++i) {
        float4 x4 = *(const float4*)(&reg2[i * 64 + 4 * tgA]);
        const float* wr = &reg1[i * 96 + 6 * cg];
        float2 w0 = *(const float2*)(wr + 0);
        float2 w1 = *(const float2*)(wr + 2);
        float2 w2 = *(const float2*)(wr + 4);
        float xa[4] = {x4.x, x4.y, x4.z, x4.w};
        float wa[6] = {w0.x, w0.y, w1.x, w1.y, w2.x, w2.y};
        #pragma unroll
        for (int cc = 0; cc < 6; ++cc)
          #pragma unroll
          for (int tt = 0; tt < 4; ++tt)
            acc[cc][tt] = fmaf(wa[cc], xa[tt], acc[cc][tt]);
      }
    }
    #pragma unroll
    for (int cc = 0; cc < 6; ++cc) {
      int cch = 6 * cg + cc;
      int seg = cch >> 5, lc = cch & 31;
      float bv = qkv_b[seg * 192 + h * 32 + lc];
      if (seg == 0) {
        #pragma unroll
        for (int tt = 0; tt < 4; ++tt)
          qs[(4 * tgA + tt) * 36 + lc] = (acc[cc][tt] + bv) * SC;
      } else if (seg == 1) {
        #pragma unroll
        for (int tt = 0; tt < 4; ++tt)
          ks[(4 * tgA + tt) * 36 + lc] = acc[cc][tt] + bv;
      } else {
        #pragma unroll
        for (int tt = 0; tt < 4; ++tt)
          vs[(4 * tgA + tt) * 36 + lc] = acc[cc][tt] + bv;
      }
    }
    __syncthreads();

    #pragma unroll
    for (int k = 0; k < 24; ++k) {
      int flat = k * 256 + tid;
      int o = flat % 192, ccc = flat / 192;
      reg1[ccc * 192 + o] = proj_w[o * DIMC + h * 32 + ccc];
    }

    float qr[32];
    {
      const float* qrow = &qs[tB * 36];
      #pragma unroll
      for (int d4 = 0; d4 < 8; ++d4) {
        float4 q4 = *(const float4*)(qrow + 4 * d4);
        qr[4*d4+0] = q4.x; qr[4*d4+1] = q4.y; qr[4*d4+2] = q4.z; qr[4*d4+3] = q4.w;
      }
    }
    float sv[16];
    #pragma unroll
    for (int mm = 0; mm < 16; ++mm) {
      const float* krow = &ks[(jB + 4 * mm) * 36];
      float a = rpb[idxv[mm] + h];
      #pragma unroll
      for (int d4 = 0; d4 < 8; ++d4) {
        float4 k4 = *(const float4*)(krow + 4 * d4);
        a = fmaf(qr[4*d4+0], k4.x, a);
        a = fmaf(qr[4*d4+1], k4.y, a);
        a = fmaf(qr[4*d4+2], k4.z, a);
        a = fmaf(qr[4*d4+3], k4.w, a);
      }
      sv[mm] = a;
    }
    float mx = sv[0];
    #pragma unroll
    for (int mm = 1; mm < 16; ++mm) mx = fmaxf(mx, sv[mm]);
    mx = fmaxf(mx, __shfl_xor(mx, 1));
    mx = fmaxf(mx, __shfl_xor(mx, 2));
    float sum = 0.f;
    #pragma unroll
    for (int mm = 0; mm < 16; ++mm) { sv[mm] = __expf(sv[mm] - mx); sum += sv[mm]; }
    sum += __shfl_xor(sum, 1);
    sum += __shfl_xor(sum, 2);
    const float inv = 1.f / sum;

    float part[32];
    #pragma unroll
    for (int dd = 0; dd < 32; ++dd) part[dd] = 0.f;
    #pragma unroll
    for (int mm = 0; mm < 16; ++mm) {
      float pvv = sv[mm] * inv;
      const float* vrow = &vs[(jB + 4 * mm) * 36];
      #pragma unroll
      for (int d4 = 0; d4 < 8; ++d4) {
        float4 v4 = *(const float4*)(vrow + 4 * d4);
        part[4*d4+0] = fmaf(pvv, v4.x, part[4*d4+0]);
        part[4*d4+1] = fmaf(pvv, v4.y, part[4*d4+1]);
        part[4*d4+2] = fmaf(pvv, v4.z, part[4*d4+2]);
        part[4*d4+3] = fmaf(pvv, v4.w, part[4*d4+3]);
      }
    }
    float p16[16];
    {
      const bool hi2 = (jB & 1);
      #pragma unroll
      for (int k2 = 0; k2 < 16; ++k2) {
        float lo_v = part[k2], hi_v = part[16 + k2];
        float sendv = hi2 ? lo_v : hi_v;
        float keepv = hi2 ? hi_v : lo_v;
        float got = __shfl_xor(sendv, 1);
        p16[k2] = keepv + got;
      }
    }
    float p8[8];
    {
      const bool hi2 = (jB & 2);
      #pragma unroll
      for (int k2 = 0; k2 < 8; ++k2) {
        float lo_v = p16[k2], hi_v = p16[8 + k2];
        float sendv = hi2 ? lo_v : hi_v;
        float keepv = hi2 ? hi_v : lo_v;
        float got = __shfl_xor(sendv, 2);
        p8[k2] = keepv + got;
      }
    }
    const int dd0 = (jB & 1) * 16 + (jB & 2) * 4;
    #pragma unroll
    for (int k2 = 0; k2 < 8; ++k2)
      reg2[(dd0 + k2) * 64 + tB] = p8[k2];

    __syncthreads();

    {
      const int o0 = 12 * ogD, t0 = 4 * tgD;
      #pragma unroll 2
      for (int cc2 = 0; cc2 < 32; ++cc2) {
        float4 a4 = *(const float4*)(&reg2[cc2 * 64 + t0]);
        const float* pr = &reg1[cc2 * 192 + o0];
        float4 b0 = *(const float4*)(pr + 0);
        float4 b1 = *(const float4*)(pr + 4);
        float4 b2 = *(const float4*)(pr + 8);
        float av[4]  = {a4.x, a4.y, a4.z, a4.w};
        float bw[12] = {b0.x, b0.y, b0.z, b0.w, b1.x, b1.y, b1.z, b1.w,
                        b2.x, b2.y, b2.z, b2.w};
        #pragma unroll
        for (int tt = 0; tt < 4; ++tt)
          #pragma unroll
          for (int oo = 0; oo < 12; ++oo)
            oacc[tt][oo] = fmaf(av[tt], bw[oo], oacc[tt][oo]);
      }
    }
  }

  {
    const int o0 = 12 * ogD, t0 = 4 * tgD;
    #pragma unroll
    for (int oo = 0; oo < 12; ++oo) {
      float pb = proj_b[o0 + oo];
      #pragma unroll
      for (int tt = 0; tt < 4; ++tt)
        outw[(size_t)(t0 + tt) * DIMC + o0 + oo] = oacc[tt][oo] + pb;
    }
  }
}

extern "C" void kernel_launch(void* const* d_in, const int* in_sizes, int n_in,
                              void* d_out, int out_size, void* d_ws, size_t ws_size,
                              hipStream_t stream) {
  const float* x      = (const float*)d_in[0];
  const float* qkv_w  = (const float*)d_in[1];
  const float* qkv_b  = (const float*)d_in[2];
  const float* proj_w = (const float*)d_in[3];
  const float* proj_b = (const float*)d_in[4];
  const float* rpb    = (const float*)d_in[5];
  const int*   ridx   = (const int*)d_in[6];
  float* out = (float*)d_out;
  const int B = in_sizes[0] / (NT * DIMC);   // 4096 windows

  if (d_ws != nullptr && ws_size >= WS_NEED) {
    hipLaunchKernelGGL(prep_kernel, dim3(99), dim3(256), 0, stream,
                       qkv_w, qkv_b, proj_w, rpb, ridx, (char*)d_ws);
    hipLaunchKernelGGL(win_attn_mfma, dim3(B), dim3(256), 0, stream,
                       x, proj_b, (const char*)d_ws, out);
  } else {
    hipLaunchKernelGGL(win_attn_kernel, dim3(B), dim3(256), 0, stream,
                       x, qkv_w, qkv_b, proj_w, proj_b, rpb, ridx, out);
  }
}